// Round 14
// baseline (1408.170 us; speedup 1.0000x reference)
//
#include <hip/hip_runtime.h>
#include <hip/hip_bf16.h>
#include <math.h>

#define NLVL 8
#define LOG2T 19
#define TSZ (1u << LOG2T)
#define NB (1 << 18)          // 64^3 Morton buckets

typedef float f32x2 __attribute__((ext_vector_type(2)));
typedef unsigned long long u64;

struct Scales { float s[NLVL]; };

static __device__ __forceinline__ unsigned short f2bf(float f) {
    unsigned u = __builtin_bit_cast(unsigned, f);
    u += 0x7fffu + ((u >> 16) & 1u);
    return (unsigned short)(u >> 16);
}
static __device__ __forceinline__ float bfbits2f(unsigned hi16) {
    return __builtin_bit_cast(float, hi16);
}
static __device__ __forceinline__ unsigned mort6(unsigned a) {
    return (a & 1) | ((a & 2) << 2) | ((a & 4) << 4) |
           ((a & 8) << 6) | ((a & 16) << 8) | ((a & 32) << 10);
}
// quantized coords (14 bit/axis) + Morton bucket key (18 bit)
static __device__ __forceinline__ void quant_key(float xx, float yy, float zz,
                                                 unsigned& qx, unsigned& qy, unsigned& qz,
                                                 unsigned& key) {
    qx = (unsigned)fminf(fmaf(xx, 8192.0f, 8192.0f), 16383.0f);
    qy = (unsigned)fminf(fmaf(yy, 8192.0f, 8192.0f), 16383.0f);
    qz = (unsigned)fminf(fmaf(zz, 8192.0f, 8192.0f), 16383.0f);
    key = mort6(qx >> 8) | (mort6(qy >> 8) << 1) | (mort6(qz >> 8) << 2);
}

// ---------------- pass 1: bucket histogram ----------------
__global__ __launch_bounds__(256) void hist_kernel(
    const float* __restrict__ x, unsigned* __restrict__ hist, int N)
{
    const int stride = gridDim.x * blockDim.x;
    for (int i = blockIdx.x * blockDim.x + threadIdx.x; i < N; i += stride) {
        float xx = __builtin_nontemporal_load(x + 3 * i + 0);
        float yy = __builtin_nontemporal_load(x + 3 * i + 1);
        float zz = __builtin_nontemporal_load(x + 3 * i + 2);
        unsigned qx, qy, qz, key;
        quant_key(xx, yy, zz, qx, qy, qz, key);
        atomicAdd(&hist[key], 1u);
    }
}

// ---------------- pass 2: exclusive scan of NB buckets (1 block) ----------------
__global__ __launch_bounds__(1024) void scan_kernel(unsigned* __restrict__ hist)
{
    __shared__ unsigned sh[1024];
    const int t = threadIdx.x;
    const int per = NB / 1024;
    const int base = t * per;
    unsigned sum = 0;
    for (int k = 0; k < per; ++k) sum += hist[base + k];
    sh[t] = sum;
    __syncthreads();
    for (int off = 1; off < 1024; off <<= 1) {
        unsigned v = (t >= off) ? sh[t - off] : 0u;
        __syncthreads();
        sh[t] += v;
        __syncthreads();
    }
    unsigned run = sh[t] - sum;   // exclusive prefix
    for (int k = 0; k < per; ++k) {
        unsigned c = hist[base + k];
        hist[base + k] = run;
        run += c;
    }
}

// ---------------- pass 3: scatter points into bucket order ----------------
__global__ __launch_bounds__(256) void scatter_kernel(
    const float* __restrict__ x, unsigned* __restrict__ hist,
    u64* __restrict__ skey, int N)
{
    const int stride = gridDim.x * blockDim.x;
    for (int i = blockIdx.x * blockDim.x + threadIdx.x; i < N; i += stride) {
        float xx = __builtin_nontemporal_load(x + 3 * i + 0);
        float yy = __builtin_nontemporal_load(x + 3 * i + 1);
        float zz = __builtin_nontemporal_load(x + 3 * i + 2);
        unsigned qx, qy, qz, key;
        quant_key(xx, yy, zz, qx, qy, qz, key);
        unsigned pos = atomicAdd(&hist[key], 1u);
        u64 pk = (u64)qx | ((u64)qy << 14) | ((u64)qz << 28) | ((u64)(unsigned)i << 42);
        skey[pos] = pk;
    }
}

// ---------------- pass 4: level-parallel encode on sorted points ----------------
// level = blockIdx.x & 7 (XCD-resident 4 MB table, r3-verified). Sorted order
// makes waves spatially compact -> corner addresses at levels 0-2 collapse to
// few distinct lines -> TCP coalescer merges them -> fewer L2 requests (the
// measured wall).
__global__ __launch_bounds__(256) void encode_sorted_kernel(
    const u64* __restrict__ skey,     // [N] packed sorted points
    const float* __restrict__ table,  // [L,T,2]
    unsigned* __restrict__ encb,      // [L][N] packed bf16x2 (sorted order)
    int N, Scales sc)
{
    const int lvl = blockIdx.x & 7;
    const int j = (blockIdx.x >> 3) * blockDim.x + threadIdx.x;
    if (j >= N) return;

    u64 sk = __builtin_nontemporal_load(skey + j);
    float px = (float)(unsigned)(sk & 16383u) * (1.0f / 16384.0f);
    float py = (float)(unsigned)((sk >> 14) & 16383u) * (1.0f / 16384.0f);
    float pz = (float)(unsigned)((sk >> 28) & 16383u) * (1.0f / 16384.0f);

    const float s = sc.s[lvl];
    float fx = fmaf(px, s, 0.5f);
    float fy = fmaf(py, s, 0.5f);
    float fz = fmaf(pz, s, 0.5f);
    float bx = floorf(fx), by = floorf(fy), bz = floorf(fz);
    float wx = fx - bx, wy = fy - by, wz = fz - bz;
    unsigned cx = (unsigned)bx, cy = (unsigned)by, cz = (unsigned)bz;

    unsigned hy0 = cy * 2654435761u;
    unsigned hy1 = hy0 + 2654435761u;
    unsigned hz0 = cz * 805459861u;
    unsigned hz1 = hz0 + 805459861u;
    unsigned cx1 = cx + 1u;
    const unsigned m = TSZ - 1u;
    const f32x2* tl = reinterpret_cast<const f32x2*>(table) + (size_t)lvl * TSZ;

    f32x2 f000 = tl[(cx  ^ hy0 ^ hz0) & m];
    f32x2 f100 = tl[(cx1 ^ hy0 ^ hz0) & m];
    f32x2 f010 = tl[(cx  ^ hy1 ^ hz0) & m];
    f32x2 f110 = tl[(cx1 ^ hy1 ^ hz0) & m];
    f32x2 f001 = tl[(cx  ^ hy0 ^ hz1) & m];
    f32x2 f101 = tl[(cx1 ^ hy0 ^ hz1) & m];
    f32x2 f011 = tl[(cx  ^ hy1 ^ hz1) & m];
    f32x2 f111 = tl[(cx1 ^ hy1 ^ hz1) & m];

    float wx0 = 1.0f - wx, wy0 = 1.0f - wy, wz0 = 1.0f - wz;
    float w00 = wx0 * wy0, w10 = wx * wy0, w01 = wx0 * wy, w11 = wx * wy;
    float a000 = w00 * wz0, a100 = w10 * wz0, a010 = w01 * wz0, a110 = w11 * wz0;
    float a001 = w00 * wz,  a101 = w10 * wz,  a011 = w01 * wz,  a111 = w11 * wz;

    float e0 = fmaf(f000.x, a000, fmaf(f100.x, a100, fmaf(f010.x, a010,
               fmaf(f110.x, a110, fmaf(f001.x, a001, fmaf(f101.x, a101,
               fmaf(f011.x, a011, f111.x * a111)))))));
    float e1 = fmaf(f000.y, a000, fmaf(f100.y, a100, fmaf(f010.y, a010,
               fmaf(f110.y, a110, fmaf(f001.y, a001, fmaf(f101.y, a101,
               fmaf(f011.y, a011, f111.y * a111)))))));

    unsigned pk = ((unsigned)f2bf(e1) << 16) | (unsigned)f2bf(e0);
    __builtin_nontemporal_store(pk, encb + (size_t)lvl * N + j);
}

// ---------------- pass 5: MLP on sorted order, scatter-out ----------------
__global__ __launch_bounds__(256) void mlp_sorted_kernel(
    const u64* __restrict__ skey,
    const unsigned* __restrict__ encb,
    const float* __restrict__ W1, const float* __restrict__ b1,
    const float* __restrict__ W2, const float* __restrict__ b2,
    float* __restrict__ out, int N)
{
    int j = blockIdx.x * blockDim.x + threadIdx.x;
    if (j >= N) return;

    u64 sk = __builtin_nontemporal_load(skey + j);
    unsigned idx = (unsigned)(sk >> 42);

    float enc[16];
    #pragma unroll
    for (int l = 0; l < NLVL; ++l) {
        unsigned pk = __builtin_nontemporal_load(encb + (size_t)l * N + j);
        enc[2 * l + 0] = bfbits2f(pk << 16);
        enc[2 * l + 1] = bfbits2f(pk & 0xffff0000u);
    }

    float h[32];
    #pragma unroll
    for (int jj = 0; jj < 32; ++jj) h[jj] = b1[jj];
    #pragma unroll
    for (int k = 0; k < 16; ++k) {
        float e = enc[k];
        #pragma unroll
        for (int jj = 0; jj < 32; ++jj)
            h[jj] = fmaf(e, W1[k * 32 + jj], h[jj]);
    }
    float z = b2[0];
    #pragma unroll
    for (int jj = 0; jj < 32; ++jj)
        z = fmaf(fmaxf(h[jj], 0.0f), W2[jj], z);

    out[idx] = 1.0f / (1.0f + __expf(-z));
}

// ---------------- r13 path (ws too small for sort) ----------------
__global__ __launch_bounds__(256) void encode_kernel(
    const float* __restrict__ x, const float* __restrict__ table,
    unsigned* __restrict__ encb, int N, Scales sc)
{
    const int lvl = blockIdx.x & 7;
    const int i = (blockIdx.x >> 3) * blockDim.x + threadIdx.x;
    if (i >= N) return;

    float xx = __builtin_nontemporal_load(x + 3 * i + 0);
    float yy = __builtin_nontemporal_load(x + 3 * i + 1);
    float zz = __builtin_nontemporal_load(x + 3 * i + 2);
    float px = (xx + 1.0f) * 0.5f;
    float py = (yy + 1.0f) * 0.5f;
    float pz = (zz + 1.0f) * 0.5f;

    const float s = sc.s[lvl];
    float fx = fmaf(px, s, 0.5f), fy = fmaf(py, s, 0.5f), fz = fmaf(pz, s, 0.5f);
    float bx = floorf(fx), by = floorf(fy), bz = floorf(fz);
    float wx = fx - bx, wy = fy - by, wz = fz - bz;
    unsigned cx = (unsigned)bx, cy = (unsigned)by, cz = (unsigned)bz;
    unsigned hy0 = cy * 2654435761u, hy1 = hy0 + 2654435761u;
    unsigned hz0 = cz * 805459861u, hz1 = hz0 + 805459861u;
    unsigned cx1 = cx + 1u;
    const unsigned m = TSZ - 1u;
    const f32x2* tl = reinterpret_cast<const f32x2*>(table) + (size_t)lvl * TSZ;

    f32x2 f000 = tl[(cx ^ hy0 ^ hz0) & m], f100 = tl[(cx1 ^ hy0 ^ hz0) & m];
    f32x2 f010 = tl[(cx ^ hy1 ^ hz0) & m], f110 = tl[(cx1 ^ hy1 ^ hz0) & m];
    f32x2 f001 = tl[(cx ^ hy0 ^ hz1) & m], f101 = tl[(cx1 ^ hy0 ^ hz1) & m];
    f32x2 f011 = tl[(cx ^ hy1 ^ hz1) & m], f111 = tl[(cx1 ^ hy1 ^ hz1) & m];

    float wx0 = 1.0f - wx, wy0 = 1.0f - wy, wz0 = 1.0f - wz;
    float w00 = wx0 * wy0, w10 = wx * wy0, w01 = wx0 * wy, w11 = wx * wy;
    float a000 = w00 * wz0, a100 = w10 * wz0, a010 = w01 * wz0, a110 = w11 * wz0;
    float a001 = w00 * wz, a101 = w10 * wz, a011 = w01 * wz, a111 = w11 * wz;

    float e0 = fmaf(f000.x,a000, fmaf(f100.x,a100, fmaf(f010.x,a010, fmaf(f110.x,a110,
               fmaf(f001.x,a001, fmaf(f101.x,a101, fmaf(f011.x,a011, f111.x*a111)))))));
    float e1 = fmaf(f000.y,a000, fmaf(f100.y,a100, fmaf(f010.y,a010, fmaf(f110.y,a110,
               fmaf(f001.y,a001, fmaf(f101.y,a101, fmaf(f011.y,a011, f111.y*a111)))))));

    unsigned pk = ((unsigned)f2bf(e1) << 16) | (unsigned)f2bf(e0);
    __builtin_nontemporal_store(pk, encb + (size_t)lvl * N + i);
}

__global__ __launch_bounds__(256) void mlp_kernel(
    const unsigned* __restrict__ encb,
    const float* __restrict__ W1, const float* __restrict__ b1,
    const float* __restrict__ W2, const float* __restrict__ b2,
    float* __restrict__ out, int N)
{
    int i = blockIdx.x * blockDim.x + threadIdx.x;
    if (i >= N) return;
    float enc[16];
    #pragma unroll
    for (int l = 0; l < NLVL; ++l) {
        unsigned pk = __builtin_nontemporal_load(encb + (size_t)l * N + i);
        enc[2 * l + 0] = bfbits2f(pk << 16);
        enc[2 * l + 1] = bfbits2f(pk & 0xffff0000u);
    }
    float h[32];
    #pragma unroll
    for (int j = 0; j < 32; ++j) h[j] = b1[j];
    #pragma unroll
    for (int k = 0; k < 16; ++k) {
        float e = enc[k];
        #pragma unroll
        for (int j = 0; j < 32; ++j) h[j] = fmaf(e, W1[k * 32 + j], h[j]);
    }
    float z = b2[0];
    #pragma unroll
    for (int j = 0; j < 32; ++j) z = fmaf(fmaxf(h[j], 0.0f), W2[j], z);
    out[i] = 1.0f / (1.0f + __expf(-z));
}

// ---------------- last-resort fused ----------------
__global__ __launch_bounds__(256) void fused_kernel(
    const float* __restrict__ x, const float* __restrict__ table,
    const float* __restrict__ W1, const float* __restrict__ b1,
    const float* __restrict__ W2, const float* __restrict__ b2,
    float* __restrict__ out, int N, Scales sc)
{
    int i = blockIdx.x * blockDim.x + threadIdx.x;
    if (i >= N) return;
    float px = (x[3 * i + 0] + 1.0f) * 0.5f;
    float py = (x[3 * i + 1] + 1.0f) * 0.5f;
    float pz = (x[3 * i + 2] + 1.0f) * 0.5f;
    float enc[16];
    #pragma unroll
    for (int l = 0; l < NLVL; ++l) {
        const float s = sc.s[l];
        float fx = fmaf(px, s, 0.5f), fy = fmaf(py, s, 0.5f), fz = fmaf(pz, s, 0.5f);
        float bx = floorf(fx), by = floorf(fy), bz = floorf(fz);
        float wx = fx - bx, wy = fy - by, wz = fz - bz;
        unsigned cx = (unsigned)bx, cy = (unsigned)by, cz = (unsigned)bz;
        unsigned hy0 = cy * 2654435761u, hy1 = hy0 + 2654435761u;
        unsigned hz0 = cz * 805459861u, hz1 = hz0 + 805459861u;
        unsigned cx1 = cx + 1u;
        const unsigned m = TSZ - 1u;
        const f32x2* tl = reinterpret_cast<const f32x2*>(table) + (size_t)l * TSZ;
        f32x2 f000 = tl[(cx ^ hy0 ^ hz0) & m], f100 = tl[(cx1 ^ hy0 ^ hz0) & m];
        f32x2 f010 = tl[(cx ^ hy1 ^ hz0) & m], f110 = tl[(cx1 ^ hy1 ^ hz0) & m];
        f32x2 f001 = tl[(cx ^ hy0 ^ hz1) & m], f101 = tl[(cx1 ^ hy0 ^ hz1) & m];
        f32x2 f011 = tl[(cx ^ hy1 ^ hz1) & m], f111 = tl[(cx1 ^ hy1 ^ hz1) & m];
        float wx0 = 1.0f - wx, wy0 = 1.0f - wy, wz0 = 1.0f - wz;
        float w00 = wx0 * wy0, w10 = wx * wy0, w01 = wx0 * wy, w11 = wx * wy;
        float a000 = w00 * wz0, a100 = w10 * wz0, a010 = w01 * wz0, a110 = w11 * wz0;
        float a001 = w00 * wz, a101 = w10 * wz, a011 = w01 * wz, a111 = w11 * wz;
        enc[2*l+0] = fmaf(f000.x,a000, fmaf(f100.x,a100, fmaf(f010.x,a010, fmaf(f110.x,a110,
                     fmaf(f001.x,a001, fmaf(f101.x,a101, fmaf(f011.x,a011, f111.x*a111)))))));
        enc[2*l+1] = fmaf(f000.y,a000, fmaf(f100.y,a100, fmaf(f010.y,a010, fmaf(f110.y,a110,
                     fmaf(f001.y,a001, fmaf(f101.y,a101, fmaf(f011.y,a011, f111.y*a111)))))));
    }
    float h[32];
    #pragma unroll
    for (int j = 0; j < 32; ++j) h[j] = b1[j];
    #pragma unroll
    for (int k = 0; k < 16; ++k) {
        float e = enc[k];
        #pragma unroll
        for (int j = 0; j < 32; ++j) h[j] = fmaf(e, W1[k * 32 + j], h[j]);
    }
    float z = b2[0];
    #pragma unroll
    for (int j = 0; j < 32; ++j) z = fmaf(fmaxf(h[j], 0.0f), W2[j], z);
    out[i] = 1.0f / (1.0f + __expf(-z));
}

extern "C" void kernel_launch(void* const* d_in, const int* in_sizes, int n_in,
                              void* d_out, int out_size, void* d_ws, size_t ws_size,
                              hipStream_t stream) {
    const float* x     = (const float*)d_in[0];
    const float* table = (const float*)d_in[1];
    const float* W1    = (const float*)d_in[2];
    const float* b1    = (const float*)d_in[3];
    const float* W2    = (const float*)d_in[4];
    const float* b2    = (const float*)d_in[5];
    float* out = (float*)d_out;

    int N = in_sizes[0] / 3;

    Scales sc;
    double B = exp(log(2048.0 / 32.0) / 7.0);
    for (int l = 0; l < NLVL; ++l)
        sc.s[l] = (float)(32.0 * pow(B, (double)l) - 1.0);

    const int block = 256;
    const int chunks = (N + block - 1) / block;
    const size_t encb_bytes = (size_t)NLVL * N * 4;        // 134 MB
    const size_t skey_bytes = (size_t)N * 8;               // 33.5 MB
    const size_t hist_bytes = (size_t)NB * 4;              // 1 MB
    const size_t need_sorted = encb_bytes + skey_bytes + hist_bytes;

    if (ws_size >= need_sorted && N <= (1 << 22)) {
        unsigned* encb = (unsigned*)d_ws;
        u64* skey = (u64*)((char*)d_ws + encb_bytes);
        unsigned* hist = (unsigned*)((char*)d_ws + encb_bytes + skey_bytes);

        hipMemsetAsync(hist, 0, hist_bytes, stream);
        hist_kernel<<<2048, block, 0, stream>>>(x, hist, N);
        scan_kernel<<<1, 1024, 0, stream>>>(hist);
        scatter_kernel<<<2048, block, 0, stream>>>(x, hist, skey, N);
        encode_sorted_kernel<<<chunks * NLVL, block, 0, stream>>>(skey, table, encb, N, sc);
        mlp_sorted_kernel<<<chunks, block, 0, stream>>>(skey, encb, W1, b1, W2, b2, out, N);
    } else if (ws_size >= encb_bytes) {
        unsigned* encb = (unsigned*)d_ws;
        encode_kernel<<<chunks * NLVL, block, 0, stream>>>(x, table, encb, N, sc);
        mlp_kernel<<<chunks, block, 0, stream>>>(encb, W1, b1, W2, b2, out, N);
    } else {
        fused_kernel<<<chunks, block, 0, stream>>>(x, table, W1, b1, W2, b2, out, N, sc);
    }
}